// Round 9
// baseline (70.341 us; speedup 1.0000x reference)
//
#include <hip/hip_runtime.h>
#include <hip/hip_bf16.h>
#include <math.h>

#define BSZ 4
#define NN 512
#define DD 64
#define NKEEP 256

typedef __attribute__((ext_vector_type(8))) short short8;
typedef __attribute__((ext_vector_type(4))) float f32x4;

__device__ __forceinline__ ushort f2bf_rne(float f) {
  union { float f; unsigned u; } v; v.f = f;
  unsigned r = v.u + 0x7fffu + ((v.u >> 16) & 1u);
  return (ushort)(r >> 16);
}
__device__ __forceinline__ float bf2f(ushort h) {
  union { unsigned u; float f; } v; v.u = ((unsigned)h) << 16;
  return v.f;
}
__device__ __forceinline__ float fast_tanh(float x) {
  float e = __builtin_amdgcn_exp2f(x * 2.8853900817779268f);
  float r = __builtin_amdgcn_rcpf(e + 1.0f);
  return 1.0f - 2.0f * r;
}

// ============ Kernel A: symmetric partial scores, e-split x2, dbuf-Y =========
// grid = 640: bid -> (b:4, eh:2, tile:80).  Block: 16 i x 128 j x 32 e.
// 8 rounds of 4 e; Y double-buffered (2 x 16 KB) -> ONE barrier per round.
// Wave w builds e = r*4 + w.  Partial scores -> plane sTp[eh*4+b].
__global__ __launch_bounds__(256, 2) void k_score(
    const float* __restrict__ x, const float* __restrict__ apw,
    const float* __restrict__ apb, const float* __restrict__ aw,
    float* __restrict__ sTp) {
  __shared__ float Xi_s[16 * 64];       // 4 KB
  __shared__ ushort Yh[2][4 * 16 * 64]; // 2 x 8 KB, swizzled
  __shared__ ushort Yl[2][4 * 16 * 64]; // 2 x 8 KB

  const int t = threadIdx.x;
  const int w = t >> 6, l = t & 63;
  const int b = blockIdx.x / 160;
  const int rem = blockIdx.x % 160;
  const int eh = rem / 80;
  const int tid = rem % 80;
  int jq, it;
  if (tid < 8)        { jq = 0; it = tid; }
  else if (tid < 24)  { jq = 1; it = tid - 8; }
  else if (tid < 48)  { jq = 2; it = tid - 24; }
  else                { jq = 3; it = tid - 48; }
  const int i0 = it * 16;
  const int jb0 = jq * 128;
  const int eh32 = eh * 32;
  const bool fast = (jb0 >= i0 + 16);

  const float* xb = x + (size_t)b * NN * DD;
  const int j0 = jb0 + w * 32;
  const bool wave_active = (j0 + 32 > i0);

  // ---- stage Xi into LDS (16 x 64 fp32) ----
  {
    const int row = t >> 4, dq = (t & 15) * 4;
    *reinterpret_cast<float4*>(&Xi_s[row * 64 + dq]) =
        *reinterpret_cast<const float4*>(xb + (size_t)(i0 + row) * DD + dq);
  }

  // ---- A fragments (Xj) split hi/lo, e-independent ----
  short8 ah[2][2], al[2][2];
  if (wave_active) {
    const int g = l >> 4;
    #pragma unroll
    for (int jt = 0; jt < 2; ++jt) {
      const int j = j0 + jt * 16 + (l & 15);
      #pragma unroll
      for (int ks = 0; ks < 2; ++ks) {
        const float* xr = xb + (size_t)j * DD + ks * 32 + g * 8;
        float4 u0 = *reinterpret_cast<const float4*>(xr);
        float4 u1 = *reinterpret_cast<const float4*>(xr + 4);
        float vv[8] = {u0.x, u0.y, u0.z, u0.w, u1.x, u1.y, u1.z, u1.w};
        short8 hh, ll;
        #pragma unroll
        for (int qq = 0; qq < 8; ++qq) {
          ushort hq = f2bf_rne(vv[qq]);
          hh[qq] = (short)hq;
          ll[qq] = (short)f2bf_rne(vv[qq] - bf2f(hq));
        }
        ah[jt][ks] = hh; al[jt][ks] = ll;
      }
    }
  }

  // ---- Y build: wave w builds e = eh32 + rnd*4 + w into buffer bf ----
  // lane covers 4 i x 4 d cells: i = i2*4 + (l>>4), dq = (l&15)*4
  const int bi_g = l >> 4;            // i sub
  const int bdq = (l & 15) * 4;       // d quad base
  auto build = [&](int rnd, int bf) {
    const int e = eh32 + rnd * 4 + w;
    float wt[4];
    #pragma unroll
    for (int k = 0; k < 4; ++k) wt[k] = apw[(bdq + k) * 64 + e];
    #pragma unroll
    for (int i2 = 0; i2 < 4; ++i2) {
      const int i = i2 * 4 + bi_g;
      float4 xv = *reinterpret_cast<const float4*>(&Xi_s[i * 64 + bdq]);
      const float p0v = xv.x * wt[0], p1v = xv.y * wt[1];
      const float p2v = xv.z * wt[2], p3v = xv.w * wt[3];
      const ushort h0 = f2bf_rne(p0v), h1 = f2bf_rne(p1v);
      const ushort h2 = f2bf_rne(p2v), h3 = f2bf_rne(p3v);
      uint2 hw, lw;
      hw.x = (uint)h0 | ((uint)h1 << 16);
      hw.y = (uint)h2 | ((uint)h3 << 16);
      lw.x = (uint)f2bf_rne(p0v - bf2f(h0)) | ((uint)f2bf_rne(p1v - bf2f(h1)) << 16);
      lw.y = (uint)f2bf_rne(p2v - bf2f(h2)) | ((uint)f2bf_rne(p3v - bf2f(h3)) << 16);
      const int byteoff = (w * 2048 + (i * 64 + bdq) * 2) ^ ((i & 7) << 4);
      *reinterpret_cast<uint2*>(reinterpret_cast<char*>(Yh[bf]) + byteoff) = hw;
      *reinterpret_cast<uint2*>(reinterpret_cast<char*>(Yl[bf]) + byteoff) = lw;
    }
  };

  const int il = l & 15, g = l >> 4;
  const int fbyte0 = ((il * 64 + g * 8) * 2) ^ ((il & 7) << 4);
  const int fbyte1 = ((il * 64 + 32 + g * 8) * 2) ^ ((il & 7) << 4);

  f32x4 srews[2];
  srews[0] = (f32x4){0.f, 0.f, 0.f, 0.f};
  srews[1] = (f32x4){0.f, 0.f, 0.f, 0.f};

  __syncthreads();  // Xi_s visible
  build(0, 0);

  #pragma unroll 1
  for (int r = 0; r < 8; ++r) {
    __syncthreads();  // Y(r) published; buf[(r+1)&1] free
    const char* Ph = reinterpret_cast<const char*>(Yh[r & 1]);
    const char* Pl = reinterpret_cast<const char*>(Yl[r & 1]);

    // prefetch e-sub 0 fragments
    short8 cbh0, cbh1, cbl0, cbl1;
    if (wave_active) {
      cbh0 = *reinterpret_cast<const short8*>(Ph + fbyte0);
      cbh1 = *reinterpret_cast<const short8*>(Ph + fbyte1);
      cbl0 = *reinterpret_cast<const short8*>(Pl + fbyte0);
      cbl1 = *reinterpret_cast<const short8*>(Pl + fbyte1);
    }
    if (r < 7) build(r + 1, (r + 1) & 1);   // overlaps with compute below

    if (wave_active) {
      #pragma unroll
      for (int p = 0; p < 4; ++p) {
        short8 nbh0, nbh1, nbl0, nbl1;
        if (p < 3) {
          nbh0 = *reinterpret_cast<const short8*>(Ph + (p + 1) * 2048 + fbyte0);
          nbh1 = *reinterpret_cast<const short8*>(Ph + (p + 1) * 2048 + fbyte1);
          nbl0 = *reinterpret_cast<const short8*>(Pl + (p + 1) * 2048 + fbyte0);
          nbl1 = *reinterpret_cast<const short8*>(Pl + (p + 1) * 2048 + fbyte1);
        }
        // 4 independent 3-deep MFMA chains: acc[jt][ks]
        f32x4 a00 = (f32x4){0.f, 0.f, 0.f, 0.f};
        f32x4 a01 = (f32x4){0.f, 0.f, 0.f, 0.f};
        f32x4 a10 = (f32x4){0.f, 0.f, 0.f, 0.f};
        f32x4 a11 = (f32x4){0.f, 0.f, 0.f, 0.f};
        a00 = __builtin_amdgcn_mfma_f32_16x16x32_bf16(ah[0][0], cbh0, a00, 0, 0, 0);
        a10 = __builtin_amdgcn_mfma_f32_16x16x32_bf16(ah[1][0], cbh0, a10, 0, 0, 0);
        a01 = __builtin_amdgcn_mfma_f32_16x16x32_bf16(ah[0][1], cbh1, a01, 0, 0, 0);
        a11 = __builtin_amdgcn_mfma_f32_16x16x32_bf16(ah[1][1], cbh1, a11, 0, 0, 0);
        a00 = __builtin_amdgcn_mfma_f32_16x16x32_bf16(ah[0][0], cbl0, a00, 0, 0, 0);
        a10 = __builtin_amdgcn_mfma_f32_16x16x32_bf16(ah[1][0], cbl0, a10, 0, 0, 0);
        a01 = __builtin_amdgcn_mfma_f32_16x16x32_bf16(ah[0][1], cbl1, a01, 0, 0, 0);
        a11 = __builtin_amdgcn_mfma_f32_16x16x32_bf16(ah[1][1], cbl1, a11, 0, 0, 0);
        a00 = __builtin_amdgcn_mfma_f32_16x16x32_bf16(al[0][0], cbh0, a00, 0, 0, 0);
        a10 = __builtin_amdgcn_mfma_f32_16x16x32_bf16(al[1][0], cbh0, a10, 0, 0, 0);
        a01 = __builtin_amdgcn_mfma_f32_16x16x32_bf16(al[0][1], cbh1, a01, 0, 0, 0);
        a11 = __builtin_amdgcn_mfma_f32_16x16x32_bf16(al[1][1], cbh1, a11, 0, 0, 0);

        const int e = eh32 + r * 4 + p;
        const float bias = apb[e], awv = aw[e];
        #pragma unroll
        for (int rr = 0; rr < 4; ++rr) {
          srews[0][rr] += awv * fast_tanh(a00[rr] + a01[rr] + bias);
          srews[1][rr] += awv * fast_tanh(a10[rr] + a11[rr] + bias);
        }
        cbh0 = nbh0; cbh1 = nbh1; cbl0 = nbl0; cbl1 = nbl1;
      }
    }
  }

  // ---- stores ----
  float* plane = sTp + ((size_t)(eh * 4 + b)) * NN * NN;
  const int iv = i0 + il;
  if (fast) {
    // mirror: register-direct, 4 rows x 64B (clean)
    #pragma unroll
    for (int jt = 0; jt < 2; ++jt)
      #pragma unroll
      for (int rr = 0; rr < 4; ++rr)
        plane[(size_t)(j0 + jt * 16 + g * 4 + rr) * NN + iv] = srews[jt][rr];
    // upper: transpose via swizzled LDS T[16][128] (aliases Yh[0], safe: all
    // compute reads of buf0 completed before the last round's barrier)
    __syncthreads();
    float* T = reinterpret_cast<float*>(Yh[0]);
    #pragma unroll
    for (int jt = 0; jt < 2; ++jt)
      #pragma unroll
      for (int rr = 0; rr < 4; ++rr) {
        const int colw = w * 32 + jt * 16 + g * 4 + rr;
        const int byteoff = ((il * 128 + colw) * 4) ^ ((il & 7) << 4);
        *reinterpret_cast<float*>(reinterpret_cast<char*>(T) + byteoff) =
            srews[jt][rr];
      }
    __syncthreads();
    const int row = t >> 4, cb = (t & 15) * 8;
    const char* Tc = reinterpret_cast<const char*>(T);
    const int base = (row * 128 + cb) * 4;
    const int sw = (row & 7) << 4;
    f32x4 v0 = *reinterpret_cast<const f32x4*>(Tc + ((base) ^ sw));
    f32x4 v1 = *reinterpret_cast<const f32x4*>(Tc + ((base + 16) ^ sw));
    *reinterpret_cast<f32x4*>(plane + (size_t)(i0 + row) * NN + jb0 + cb) = v0;
    *reinterpret_cast<f32x4*>(plane + (size_t)(i0 + row) * NN + jb0 + cb + 4) = v1;
  } else if (wave_active) {
    #pragma unroll
    for (int jt = 0; jt < 2; ++jt)
      #pragma unroll
      for (int rr = 0; rr < 4; ++rr) {
        const int jv = j0 + jt * 16 + g * 4 + rr;
        const float v = srews[jt][rr];
        if (jv >= iv) plane[(size_t)iv * NN + jv] = v;
        if (jv > iv) plane[(size_t)jv * NN + iv] = v;
      }
  }
}

// ====== Kernel B: 2 rows/block, 4 waves j-split: softmax+agg+h+BN+SELU+s =====
__global__ __launch_bounds__(256) void k_soft(
    const float* __restrict__ x, const float* __restrict__ sTp,
    const float* __restrict__ pwa, const float* __restrict__ pwab,
    const float* __restrict__ pwoa, const float* __restrict__ pwob,
    const float* __restrict__ gam, const float* __restrict__ bet,
    const float* __restrict__ mu, const float* __restrict__ var,
    const float* __restrict__ poolw, const float* __restrict__ poolb,
    float* __restrict__ h, float* __restrict__ s) {
  __shared__ float ssc[2][512];
  __shared__ float srm[2][4], srs[2][4];
  __shared__ float sagg[4][2][64];
  __shared__ float rag[2][64], xis[2][64];

  const int t = threadIdx.x;
  const int w = t >> 6, l = t & 63;
  const int b = blockIdx.x >> 8;
  const int rp = blockIdx.x & 255;
  const int i_r0 = rp * 2, i_r1 = i_r0 + 1;
  const float* xb = x + (size_t)b * NN * DD;
  const float* pl0 = sTp + (size_t)b * NN * NN;
  const float* pl1 = sTp + (size_t)(4 + b) * NN * NN;
  const int jw = w * 128;

  const size_t o0 = (size_t)i_r0 * NN + jw + l;
  const size_t o1 = (size_t)i_r1 * NN + jw + l;
  float r0a = pl0[o0] + pl1[o0];
  float r0b = pl0[o0 + 64] + pl1[o0 + 64];
  float r1a = pl0[o1] + pl1[o1];
  float r1b = pl0[o1 + 64] + pl1[o1 + 64];
  float m0 = fmaxf(r0a, r0b), m1 = fmaxf(r1a, r1b);
  #pragma unroll
  for (int off = 32; off; off >>= 1) {
    m0 = fmaxf(m0, __shfl_xor(m0, off, 64));
    m1 = fmaxf(m1, __shfl_xor(m1, off, 64));
  }
  if (l == 0) { srm[0][w] = m0; srm[1][w] = m1; }
  __syncthreads();
  m0 = fmaxf(fmaxf(srm[0][0], srm[0][1]), fmaxf(srm[0][2], srm[0][3]));
  m1 = fmaxf(fmaxf(srm[1][0], srm[1][1]), fmaxf(srm[1][2], srm[1][3]));

  const float L2E = 1.4426950408889634f;
  float e0a = __builtin_amdgcn_exp2f((r0a - m0) * L2E);
  float e0b = __builtin_amdgcn_exp2f((r0b - m0) * L2E);
  float e1a = __builtin_amdgcn_exp2f((r1a - m1) * L2E);
  float e1b = __builtin_amdgcn_exp2f((r1b - m1) * L2E);
  float ps0 = e0a + e0b, ps1 = e1a + e1b;
  #pragma unroll
  for (int off = 32; off; off >>= 1) {
    ps0 += __shfl_xor(ps0, off, 64);
    ps1 += __shfl_xor(ps1, off, 64);
  }
  if (l == 0) { srs[0][w] = ps0; srs[1][w] = ps1; }
  __syncthreads();
  const float inv0 = 1.f / (srs[0][0] + srs[0][1] + srs[0][2] + srs[0][3]);
  const float inv1 = 1.f / (srs[1][0] + srs[1][1] + srs[1][2] + srs[1][3]);
  ssc[0][jw + l] = e0a * inv0;
  ssc[0][jw + 64 + l] = e0b * inv0;
  ssc[1][jw + l] = e1a * inv1;
  ssc[1][jw + 64 + l] = e1b * inv1;
  __syncthreads();

  // agg GEMV: 4 independent chains (2 rows x 2 j-substrides)
  float g0a = 0.f, g0b = 0.f, g1a = 0.f, g1b = 0.f;
  #pragma unroll 4
  for (int jj = 0; jj < 128; jj += 2) {
    const int j = jw + jj;
    const float xv0 = xb[(size_t)j * DD + l];
    const float xv1 = xb[(size_t)(j + 1) * DD + l];
    g0a = fmaf(ssc[0][j], xv0, g0a);
    g1a = fmaf(ssc[1][j], xv0, g1a);
    g0b = fmaf(ssc[0][j + 1], xv1, g0b);
    g1b = fmaf(ssc[1][j + 1], xv1, g1b);
  }
  sagg[w][0][l] = g0a + g0b;
  sagg[w][1][l] = g1a + g1b;
  __syncthreads();

  if (w < 2) {
    const int irow = i_r0 + w;
    rag[w][l] = sagg[0][w][l] + sagg[1][w][l] + sagg[2][w][l] + sagg[3][w][l];
    xis[w][l] = xb[(size_t)irow * DD + l];
    float acc = 0.f;
    #pragma unroll 8
    for (int d = 0; d < 64; ++d) {
      acc = fmaf(rag[w][d], pwa[d * 64 + l], acc);
      acc = fmaf(xis[w][d], pwoa[d * 64 + l], acc);
    }
    acc += pwab[l] + pwob[l];
    float hb = (acc - mu[l]) * rsqrtf(var[l] + 1e-5f) * gam[l] + bet[l];
    const float SC = 1.0507009873554805f, AL = 1.6732632423543772f;
    float hv = hb > 0.f ? SC * hb : SC * AL * expm1f(hb);
    h[((size_t)(b * NN + irow)) * DD + l] = hv;

    float p = hv * poolw[l];
    #pragma unroll
    for (int off = 32; off; off >>= 1) p += __shfl_xor(p, off, 64);
    if (l == 0) s[b * NN + irow] = 1.f / (1.f + expf(-(p + poolb[0])));
  }
}

// ====== Kernel C1: per-batch rank selection (exact tie semantics) ============
__global__ __launch_bounds__(512) void k_topk(
    const float* __restrict__ s, int* __restrict__ invi,
    float* __restrict__ sval) {
  __shared__ float sv[NN];
  const int b = blockIdx.x, t = threadIdx.x;
  sv[t] = s[b * NN + t];
  __syncthreads();

  const float my = sv[t];
  int r = 0;
  #pragma unroll 4
  for (int j0 = 0; j0 < NN; j0 += 4) {
    float4 v = *reinterpret_cast<const float4*>(&sv[j0]);
    r += (v.x > my) || (v.x == my && (j0 + 0) < t);
    r += (v.y > my) || (v.y == my && (j0 + 1) < t);
    r += (v.z > my) || (v.z == my && (j0 + 2) < t);
    r += (v.w > my) || (v.w == my && (j0 + 3) < t);
  }
  if (r < NKEEP) { invi[b * NKEEP + r] = t; sval[b * NKEEP + r] = my; }
}

// ====== Kernel C2: parallel gather: out[b,kk,:] = h[b,inv[kk],:]*sval[kk] ====
__global__ __launch_bounds__(256) void k_gather(
    const int* __restrict__ invi, const float* __restrict__ sval,
    const float* __restrict__ h, float* __restrict__ out) {
  const int b = blockIdx.x >> 4, kg = blockIdx.x & 15;
  const int t = threadIdx.x;
  const int kk = kg * 16 + (t >> 4);
  const int d4 = (t & 15) * 4;
  const int i = invi[b * NKEEP + kk];
  const float svv = sval[b * NKEEP + kk];
  float4 v = *reinterpret_cast<const float4*>(h + ((size_t)(b * NN + i)) * DD + d4);
  v.x *= svv; v.y *= svv; v.z *= svv; v.w *= svv;
  *reinterpret_cast<float4*>(out + ((size_t)(b * NKEEP + kk)) * DD + d4) = v;
}

extern "C" void kernel_launch(void* const* d_in, const int* in_sizes, int n_in,
                              void* d_out, int out_size, void* d_ws, size_t ws_size,
                              hipStream_t stream) {
  const float* x     = (const float*)d_in[0];
  const float* apw   = (const float*)d_in[1];
  const float* apb   = (const float*)d_in[2];
  const float* aw    = (const float*)d_in[3];
  const float* pwa   = (const float*)d_in[4];
  const float* pwab  = (const float*)d_in[5];
  const float* pwoa  = (const float*)d_in[6];
  const float* pwob  = (const float*)d_in[7];
  const float* gam   = (const float*)d_in[8];
  const float* bet   = (const float*)d_in[9];
  const float* mu    = (const float*)d_in[10];
  const float* var   = (const float*)d_in[11];
  const float* poolw = (const float*)d_in[12];
  const float* poolb = (const float*)d_in[13];
  float* out = (float*)d_out;

  float* sTp = (float*)d_ws;                      // 2 planes x 4 MB = 8 MB
  float* h   = sTp + (size_t)2 * BSZ * NN * NN;   // 512 KB
  float* s   = h + (size_t)BSZ * NN * DD;         // 8 KB
  int* invi  = (int*)(s + BSZ * NN);              // 4 KB
  float* sval = (float*)(invi + BSZ * NKEEP);     // 4 KB

  k_score<<<640, 256, 0, stream>>>(x, apw, apb, aw, sTp);
  k_soft<<<BSZ * 256, 256, 0, stream>>>(x, sTp, pwa, pwab, pwoa, pwob,
                                        gam, bet, mu, var, poolw, poolb, h, s);
  k_topk<<<BSZ, 512, 0, stream>>>(s, invi, sval);
  k_gather<<<BSZ * 16, 256, 0, stream>>>(invi, sval, h, out);
}